// Round 9
// baseline (492.482 us; speedup 1.0000x reference)
//
#include <hip/hip_runtime.h>
#include <hip/hip_bf16.h>

#define N_NODES 50000
#define N_EDGES 600000
#define N_PAIRS 100000
#define NBUCK 512   // pair-sort buckets: src>>7 (391 used)

typedef __attribute__((ext_vector_type(8))) short bf16x8;
typedef __attribute__((ext_vector_type(4))) float f32x4;

__device__ inline unsigned short f2b(float f) {
    unsigned u = __float_as_uint(f);
    unsigned r = u + 0x7fff + ((u >> 16) & 1);
    return (unsigned short)(r >> 16);
}
__device__ inline float b2f(unsigned short h) {
    return __uint_as_float(((unsigned)h) << 16);
}

// ---- convert x to bf16 (A1 ld256 + compact xb16) AND edge-degree histogram ----
__global__ void k_convert_x(const float* __restrict__ x, unsigned short* __restrict__ A1,
                            unsigned short* __restrict__ xb16,
                            const int* __restrict__ edge_dst, int* __restrict__ deg) {
    int idx = blockIdx.x * blockDim.x + threadIdx.x;
    if (idx < N_EDGES) atomicAdd(&deg[edge_dst[idx]], 1);
    if (idx >= N_NODES * 32) return;
    int row = idx >> 5, c4 = (idx & 31) * 4;
    float4 v = *(const float4*)(x + row * 128 + c4);
    unsigned lo = (unsigned)f2b(v.x) | ((unsigned)f2b(v.y) << 16);
    unsigned hi = (unsigned)f2b(v.z) | ((unsigned)f2b(v.w) << 16);
    uint2 o; o.x = lo; o.y = hi;
    *(uint2*)(A1 + row * 256 + c4) = o;
    *(uint2*)(xb16 + row * 128 + c4) = o;
}

// ---- build transposed bf16 weights ----
__global__ void k_prep_w(const float* __restrict__ Ws1, const float* __restrict__ Wn1,
                         const float* __restrict__ Ws2, const float* __restrict__ Wn2,
                         const float* __restrict__ Wd1, const float* __restrict__ Wd2,
                         unsigned short* __restrict__ WT1, unsigned short* __restrict__ WT2,
                         unsigned short* __restrict__ WdT1, unsigned short* __restrict__ WdT2) {
    int id = blockIdx.x * blockDim.x + threadIdx.x;
    if (id < 32768) {
        int k = id & 255, n = id >> 8;
        float v = (k < 128) ? Ws1[k * 128 + n] : Wn1[(k - 128) * 128 + n];
        WT1[n * 256 + k] = f2b(v);
    } else if (id < 65536) {
        int r = id - 32768; int k = r & 255, n = r >> 8;
        float v = (k < 128) ? Ws2[k * 128 + n] : Wn2[(k - 128) * 128 + n];
        WT2[n * 256 + k] = f2b(v);
    } else if (id < 81920) {
        int r = id - 65536; int k = r & 127, n = r >> 7;
        WdT1[n * 128 + k] = f2b(Wd1[k * 128 + n]);
    } else if (id < 98304) {
        int r = id - 81920; int k = r & 127, n = r >> 7;
        WdT2[n * 128 + k] = f2b(Wd2[k * 128 + n]);
    }
}

// ---- CSR build ----
__global__ void k_scan1(const int* __restrict__ deg, int* __restrict__ row_ptr,
                        int* __restrict__ bsum, int n) {
    __shared__ int tmp[1024];
    int i = blockIdx.x * 1024 + threadIdx.x;
    int d = (i < n) ? deg[i] : 0;
    tmp[threadIdx.x] = d;
    __syncthreads();
    int run = d;
    for (int off = 1; off < 1024; off <<= 1) {
        int t = (threadIdx.x >= off) ? tmp[threadIdx.x - off] : 0;
        __syncthreads();
        run += t;
        tmp[threadIdx.x] = run;
        __syncthreads();
    }
    if (i < n) row_ptr[i] = run - d;
    if (threadIdx.x == 1023) bsum[blockIdx.x] = run;
}

__global__ void k_add(int* __restrict__ row_ptr, int* __restrict__ cursor,
                      const int* __restrict__ bsum, int n) {
    __shared__ int prefix;
    if (threadIdx.x == 0) {
        int acc = 0;
        for (int j = 0; j < (int)blockIdx.x; j++) acc += bsum[j];
        prefix = acc;
    }
    __syncthreads();
    int i = blockIdx.x * 1024 + threadIdx.x;
    if (i < n) {
        int v = row_ptr[i] + prefix;
        row_ptr[i] = v;
        cursor[i] = v;
    }
    if (i == 0) row_ptr[n] = N_EDGES;
}

__global__ void k_scatter(const int* __restrict__ src, const int* __restrict__ dst,
                          int* __restrict__ cursor, int* __restrict__ colA) {
    int e = blockIdx.x * blockDim.x + threadIdx.x;
    if (e < N_EDGES) {
        int d = dst[e];
        int slot = atomicAdd(&cursor[d], 1);
        colA[slot] = src[e];
    }
}

// ---- pair counting-sort by src>>7 (locality for decoder gathers) ----
__global__ void k_phist(const int* __restrict__ pos_src, const int* __restrict__ neg_src,
                        int* __restrict__ hist) {
    int p = blockIdx.x * 256 + threadIdx.x;
    if (p < N_PAIRS) atomicAdd(&hist[pos_src[p] >> 7], 1);
    else if (p < 2 * N_PAIRS) atomicAdd(&hist[neg_src[p - N_PAIRS] >> 7], 1);
}

__global__ void k_pscan(const int* __restrict__ hist, int* __restrict__ boff) {
    __shared__ int tmp[NBUCK];
    int t = threadIdx.x;
    int v = hist[t];
    tmp[t] = v;
    __syncthreads();
    int run = v;
    for (int off = 1; off < NBUCK; off <<= 1) {
        int u = (t >= off) ? tmp[t - off] : 0;
        __syncthreads();
        run += u;
        tmp[t] = run;
        __syncthreads();
    }
    boff[t] = run - v;   // exclusive prefix
}

__global__ void k_psort(const int* __restrict__ pos_src, const int* __restrict__ neg_src,
                        int* __restrict__ boff, int* __restrict__ perm) {
    int p = blockIdx.x * 256 + threadIdx.x;
    int key;
    if (p < N_PAIRS) key = pos_src[p] >> 7;
    else if (p < 2 * N_PAIRS) key = neg_src[p - N_PAIRS] >> 7;
    else return;
    int slot = atomicAdd(&boff[key], 1);
    perm[slot] = p;
}

// ---- mean aggregation (bf16 input): 4 nodes per wave (16 lanes x 16B each) ----
__global__ __launch_bounds__(256) void k_agg(const unsigned short* __restrict__ hb, int ldh,
                                             const int* __restrict__ row_ptr,
                                             const int* __restrict__ colA,
                                             unsigned short* __restrict__ outm, int ldo) {
    int wave = (blockIdx.x * blockDim.x + threadIdx.x) >> 6;
    int lane = threadIdx.x & 63;
    int q = lane >> 4, ql = lane & 15;
    int w = wave * 4 + q;
    if (w >= N_NODES) w = N_NODES - 1;
    int s = row_ptr[w], e = row_ptr[w + 1];
    float a[8];
#pragma unroll
    for (int j = 0; j < 8; j++) a[j] = 0.f;
    for (int base = s; base < e; base += 16) {
        int ce = (base + ql < e) ? colA[base + ql] : 0;
        int cnt = min(16, e - base);
        int ei[16];
#pragma unroll
        for (int j = 0; j < 16; j++) {
            int sl = (j < cnt) ? j : (cnt - 1);
            ei[j] = __shfl(ce, (q << 4) + sl, 64);
        }
        uint4 v[16];
#pragma unroll
        for (int j = 0; j < 16; j++)
            v[j] = *(const uint4*)(hb + (size_t)ei[j] * ldh + ql * 8);
#pragma unroll
        for (int j = 0; j < 16; j += 2) {
            const unsigned* p0 = (const unsigned*)&v[j];
            const unsigned* p1 = (const unsigned*)&v[j + 1];
            if (j + 1 < cnt) {
#pragma unroll
                for (int t = 0; t < 4; t++) {
                    a[2 * t] += b2f(p0[t] & 0xffff) + b2f(p1[t] & 0xffff);
                    a[2 * t + 1] += b2f(p0[t] >> 16) + b2f(p1[t] >> 16);
                }
            } else if (j < cnt) {
#pragma unroll
                for (int t = 0; t < 4; t++) {
                    a[2 * t] += b2f(p0[t] & 0xffff);
                    a[2 * t + 1] += b2f(p0[t] >> 16);
                }
            }
        }
    }
    float rd = 1.0f / (float)max(e - s, 1);
    uint4 o;
    unsigned* op = (unsigned*)&o;
#pragma unroll
    for (int t = 0; t < 4; t++)
        op[t] = (unsigned)f2b(a[2 * t] * rd) | ((unsigned)f2b(a[2 * t + 1] * rd) << 16);
    *(uint4*)(outm + (size_t)w * ldo + ql * 8) = o;
}

// ---- SAGE layer GEMM: 32 rows/wave, weight frags grouped 8-in-flight ----
__global__ __launch_bounds__(256) void k_gemm(const unsigned short* __restrict__ A, int lda, int K,
                                              const unsigned short* __restrict__ BT,
                                              const float* __restrict__ bias,
                                              unsigned short* __restrict__ Hout, int ldo,
                                              int M, int relu) {
    int wv = threadIdx.x >> 6, lane = threadIdx.x & 63;
    int lr = lane & 15, lq = lane >> 4;
    int r0 = blockIdx.x * 128 + wv * 32;
    int arow0 = min(r0 + lr, M - 1);
    int arow1 = min(r0 + 16 + lr, M - 1);
    f32x4 acc[2][8];
    f32x4 zero = {0.f, 0.f, 0.f, 0.f};
#pragma unroll
    for (int m = 0; m < 2; m++)
#pragma unroll
        for (int ct = 0; ct < 8; ct++) acc[m][ct] = zero;
    for (int kb = 0; kb < K; kb += 32) {
        int ka = kb + lq * 8;
        bf16x8 wf[8];
#pragma unroll
        for (int ct = 0; ct < 8; ct++)
            wf[ct] = *(const bf16x8*)(BT + (ct * 16 + lr) * K + ka);
        bf16x8 af0 = *(const bf16x8*)(A + (size_t)arow0 * lda + ka);
        bf16x8 af1 = *(const bf16x8*)(A + (size_t)arow1 * lda + ka);
#pragma unroll
        for (int ct = 0; ct < 8; ct++) {
            acc[0][ct] = __builtin_amdgcn_mfma_f32_16x16x32_bf16(af0, wf[ct], acc[0][ct], 0, 0, 0);
            acc[1][ct] = __builtin_amdgcn_mfma_f32_16x16x32_bf16(af1, wf[ct], acc[1][ct], 0, 0, 0);
        }
    }
#pragma unroll
    for (int m = 0; m < 2; m++) {
#pragma unroll
        for (int ct = 0; ct < 8; ct++) {
            int colc = ct * 16 + lr;
            float bv = bias[colc];
#pragma unroll
            for (int r = 0; r < 4; r++) {
                int row = r0 + m * 16 + lq * 4 + r;
                if (row < M) {
                    float v = acc[m][ct][r] + bv;
                    if (relu) v = fmaxf(v, 0.f);
                    Hout[(size_t)row * ldo + colc] = f2b(v);
                }
            }
        }
    }
}

// ---- decoder MLP v6: 1-wave blocks, src-sorted pair order via perm ----
__global__ __launch_bounds__(64) void k_mlp(const unsigned short* __restrict__ h2b,
                                            const int* __restrict__ perm,
                                            const int* __restrict__ pos_src,
                                            const int* __restrict__ pos_dst,
                                            const int* __restrict__ neg_src,
                                            const int* __restrict__ neg_dst,
                                            const unsigned short* __restrict__ WdT1,
                                            const unsigned short* __restrict__ WdT2,
                                            const float* __restrict__ bd1,
                                            const float* __restrict__ bd2,
                                            const float* __restrict__ Wd3,
                                            const float* __restrict__ bd3,
                                            float* __restrict__ out, int P2) {
    __shared__ unsigned short t1[32][136];   // 8,704 B
    const int lane = threadIdx.x & 63, lr = lane & 15, lq = lane >> 4;
    const int row0 = blockIdx.x * 32;
    int p0 = perm[min(row0 + lr, P2 - 1)];
    int p1 = perm[min(row0 + 16 + lr, P2 - 1)];
    int s0i = (p0 < N_PAIRS) ? pos_src[p0] : neg_src[p0 - N_PAIRS];
    int d0i = (p0 < N_PAIRS) ? pos_dst[p0] : neg_dst[p0 - N_PAIRS];
    int s1i = (p1 < N_PAIRS) ? pos_src[p1] : neg_src[p1 - N_PAIRS];
    int d1i = (p1 < N_PAIRS) ? pos_dst[p1] : neg_dst[p1 - N_PAIRS];
    uint4 za0[4], zb0[4], za1[4], zb1[4];
#pragma unroll
    for (int kb = 0; kb < 4; kb++) {
        int ka = kb * 32 + lq * 8;
        za0[kb] = *(const uint4*)(h2b + (size_t)s0i * 128 + ka);
        zb0[kb] = *(const uint4*)(h2b + (size_t)d0i * 128 + ka);
        za1[kb] = *(const uint4*)(h2b + (size_t)s1i * 128 + ka);
        zb1[kb] = *(const uint4*)(h2b + (size_t)d1i * 128 + ka);
    }
    bf16x8 af0[4], af1[4];
#pragma unroll
    for (int kb = 0; kb < 4; kb++) {
        unsigned r0v[4], r1v[4];
        const unsigned* a0p = (const unsigned*)&za0[kb];
        const unsigned* b0p = (const unsigned*)&zb0[kb];
        const unsigned* a1p = (const unsigned*)&za1[kb];
        const unsigned* b1p = (const unsigned*)&zb1[kb];
#pragma unroll
        for (int j = 0; j < 4; j++) {
            unsigned short lo0 = f2b(b2f(a0p[j] & 0xffff) * b2f(b0p[j] & 0xffff));
            unsigned short hi0 = f2b(b2f(a0p[j] >> 16) * b2f(b0p[j] >> 16));
            r0v[j] = (unsigned)lo0 | ((unsigned)hi0 << 16);
            unsigned short lo1 = f2b(b2f(a1p[j] & 0xffff) * b2f(b1p[j] & 0xffff));
            unsigned short hi1 = f2b(b2f(a1p[j] >> 16) * b2f(b1p[j] >> 16));
            r1v[j] = (unsigned)lo1 | ((unsigned)hi1 << 16);
        }
        af0[kb] = *(const bf16x8*)r0v;
        af1[kb] = *(const bf16x8*)r1v;
    }
    f32x4 zero = {0.f, 0.f, 0.f, 0.f};
    f32x4 acc[2][8];
#pragma unroll
    for (int m = 0; m < 2; m++)
#pragma unroll
        for (int ct = 0; ct < 8; ct++) acc[m][ct] = zero;
#pragma unroll
    for (int kb = 0; kb < 4; kb++) {
        int ka = kb * 32 + lq * 8;
        bf16x8 wf[8];
#pragma unroll
        for (int ct = 0; ct < 8; ct++)
            wf[ct] = *(const bf16x8*)(WdT1 + (ct * 16 + lr) * 128 + ka);
#pragma unroll
        for (int ct = 0; ct < 8; ct++) {
            acc[0][ct] = __builtin_amdgcn_mfma_f32_16x16x32_bf16(af0[kb], wf[ct], acc[0][ct], 0, 0, 0);
            acc[1][ct] = __builtin_amdgcn_mfma_f32_16x16x32_bf16(af1[kb], wf[ct], acc[1][ct], 0, 0, 0);
        }
    }
#pragma unroll
    for (int m = 0; m < 2; m++)
#pragma unroll
        for (int ct = 0; ct < 8; ct++) {
            int colc = ct * 16 + lr;
            float bv = bd1[colc];
#pragma unroll
            for (int r = 0; r < 4; r++) {
                float v = fmaxf(acc[m][ct][r] + bv, 0.f);
                t1[m * 16 + lq * 4 + r][colc] = f2b(v);
            }
        }
    __syncthreads();
#pragma unroll
    for (int m = 0; m < 2; m++)
#pragma unroll
        for (int ct = 0; ct < 8; ct++) acc[m][ct] = zero;
#pragma unroll
    for (int kb = 0; kb < 4; kb++) {
        int ka = kb * 32 + lq * 8;
        bf16x8 wf[8];
#pragma unroll
        for (int ct = 0; ct < 8; ct++)
            wf[ct] = *(const bf16x8*)(WdT2 + (ct * 16 + lr) * 128 + ka);
        bf16x8 bf0 = *(const bf16x8*)(&t1[lr][ka]);
        bf16x8 bf1 = *(const bf16x8*)(&t1[16 + lr][ka]);
#pragma unroll
        for (int ct = 0; ct < 8; ct++) {
            acc[0][ct] = __builtin_amdgcn_mfma_f32_16x16x32_bf16(bf0, wf[ct], acc[0][ct], 0, 0, 0);
            acc[1][ct] = __builtin_amdgcn_mfma_f32_16x16x32_bf16(bf1, wf[ct], acc[1][ct], 0, 0, 0);
        }
    }
    float sc[2][4] = {{0.f, 0.f, 0.f, 0.f}, {0.f, 0.f, 0.f, 0.f}};
#pragma unroll
    for (int ct = 0; ct < 8; ct++) {
        int colc = ct * 16 + lr;
        float bv = bd2[colc];
        float w3 = Wd3[colc];
#pragma unroll
        for (int m = 0; m < 2; m++)
#pragma unroll
            for (int r = 0; r < 4; r++) {
                float v = fmaxf(acc[m][ct][r] + bv, 0.f);
                sc[m][r] += v * w3;
            }
    }
#pragma unroll
    for (int mm = 1; mm < 16; mm <<= 1)
#pragma unroll
        for (int m = 0; m < 2; m++)
#pragma unroll
            for (int r = 0; r < 4; r++) sc[m][r] += __shfl_xor(sc[m][r], mm, 64);
    if (lr == 0) {
        float b3 = bd3[0];
#pragma unroll
        for (int m = 0; m < 2; m++)
#pragma unroll
            for (int r = 0; r < 4; r++) {
                int g = row0 + m * 16 + lq * 4 + r;
                if (g < P2) out[perm[g]] = sc[m][r] + b3;
            }
    }
}

static inline size_t alignup(size_t v) { return (v + 255) & ~(size_t)255; }

extern "C" void kernel_launch(void* const* d_in, const int* in_sizes, int n_in,
                              void* d_out, int out_size, void* d_ws, size_t ws_size,
                              hipStream_t stream) {
    const float* x = (const float*)d_in[0];
    const int* edge_src = (const int*)d_in[1];
    const int* edge_dst = (const int*)d_in[2];
    const int* pos_src = (const int*)d_in[3];
    const int* pos_dst = (const int*)d_in[4];
    const int* neg_src = (const int*)d_in[5];
    const int* neg_dst = (const int*)d_in[6];
    const float* Ws1 = (const float*)d_in[7];
    const float* Wn1 = (const float*)d_in[8];
    const float* b1 = (const float*)d_in[9];
    const float* Ws2 = (const float*)d_in[10];
    const float* Wn2 = (const float*)d_in[11];
    const float* b2 = (const float*)d_in[12];
    const float* Wd1 = (const float*)d_in[13];
    const float* bd1 = (const float*)d_in[14];
    const float* Wd2 = (const float*)d_in[15];
    const float* bd2 = (const float*)d_in[16];
    const float* Wd3 = (const float*)d_in[17];
    const float* bd3 = (const float*)d_in[18];
    float* out = (float*)d_out;

    char* p = (char*)d_ws;
    int* deg = (int*)p;            p += alignup(N_NODES * 4);
    int* row_ptr = (int*)p;        p += alignup((N_NODES + 1) * 4);
    int* cursor = (int*)p;         p += alignup(N_NODES * 4);
    int* bsum = (int*)p;           p += alignup(64 * 4);
    int* colA = (int*)p;           p += alignup(N_EDGES * 4);
    int* hist = (int*)p;           p += alignup(NBUCK * 4);
    int* boff = (int*)p;           p += alignup(NBUCK * 4);
    int* perm = (int*)p;           p += alignup(2 * N_PAIRS * 4);
    unsigned short* A1 = (unsigned short*)p;  p += alignup((size_t)N_NODES * 256 * 2);
    unsigned short* A2 = (unsigned short*)p;  p += alignup((size_t)N_NODES * 256 * 2);
    unsigned short* h2b = (unsigned short*)p; p += alignup((size_t)N_NODES * 128 * 2);
    unsigned short* WT1 = (unsigned short*)p;  p += alignup(32768 * 2);
    unsigned short* WT2 = (unsigned short*)p;  p += alignup(32768 * 2);
    unsigned short* WdT1 = (unsigned short*)p; p += alignup(16384 * 2);
    unsigned short* WdT2 = (unsigned short*)p; p += alignup(16384 * 2);
    unsigned short* xb16 = h2b;   // aliased: consumed by agg1 before gemm2 writes h2b

    hipMemsetAsync(deg, 0, N_NODES * 4, stream);
    hipMemsetAsync(hist, 0, NBUCK * 4, stream);

    k_convert_x<<<(N_NODES * 32 + 255) / 256, 256, 0, stream>>>(x, A1, xb16, edge_dst, deg);
    k_prep_w<<<384, 256, 0, stream>>>(Ws1, Wn1, Ws2, Wn2, Wd1, Wd2, WT1, WT2, WdT1, WdT2);

    // pair sort (independent of CSR chain; overlaps fine on one stream)
    k_phist<<<(2 * N_PAIRS + 255) / 256, 256, 0, stream>>>(pos_src, neg_src, hist);
    k_pscan<<<1, NBUCK, 0, stream>>>(hist, boff);
    k_psort<<<(2 * N_PAIRS + 255) / 256, 256, 0, stream>>>(pos_src, neg_src, boff, perm);

    int nb1 = (N_NODES + 1023) / 1024;
    k_scan1<<<nb1, 1024, 0, stream>>>(deg, row_ptr, bsum, N_NODES);
    k_add<<<nb1, 1024, 0, stream>>>(row_ptr, cursor, bsum, N_NODES);
    k_scatter<<<(N_EDGES + 255) / 256, 256, 0, stream>>>(edge_src, edge_dst, cursor, colA);

    int nagg = (N_NODES + 15) / 16;

    // layer 1 (bf16 aggregation from compact xb16)
    k_agg<<<nagg, 256, 0, stream>>>(xb16, 128, row_ptr, colA, A1 + 128, 256);
    k_gemm<<<(N_NODES + 127) / 128, 256, 0, stream>>>(A1, 256, 256, WT1, b1, A2, 256, N_NODES, 1);

    // layer 2
    k_agg<<<nagg, 256, 0, stream>>>(A2, 256, row_ptr, colA, A2 + 128, 256);
    k_gemm<<<(N_NODES + 127) / 128, 256, 0, stream>>>(A2, 256, 256, WT2, b2, h2b, 128, N_NODES, 0);

    // decoder: fused gather + MLP in src-sorted order
    k_mlp<<<(N_PAIRS * 2 + 31) / 32, 64, 0, stream>>>(h2b, perm, pos_src, pos_dst, neg_src, neg_dst,
                                                      WdT1, WdT2, bd1, bd2, Wd3, bd3,
                                                      out, N_PAIRS * 2);
}

// Round 10
// 335.167 us; speedup vs baseline: 1.4694x; 1.4694x over previous
//
#include <hip/hip_runtime.h>
#include <hip/hip_bf16.h>

#define N_NODES 50000
#define N_EDGES 600000
#define N_PAIRS 100000

typedef __attribute__((ext_vector_type(8))) short bf16x8;
typedef __attribute__((ext_vector_type(4))) float f32x4;

__device__ inline unsigned short f2b(float f) {
    unsigned u = __float_as_uint(f);
    unsigned r = u + 0x7fff + ((u >> 16) & 1);
    return (unsigned short)(r >> 16);
}
__device__ inline float b2f(unsigned short h) {
    return __uint_as_float(((unsigned)h) << 16);
}

// ---- convert x to bf16 (A1 ld256 + compact xb16) AND edge-degree histogram ----
__global__ void k_convert_x(const float* __restrict__ x, unsigned short* __restrict__ A1,
                            unsigned short* __restrict__ xb16,
                            const int* __restrict__ edge_dst, int* __restrict__ deg) {
    int idx = blockIdx.x * blockDim.x + threadIdx.x;
    if (idx < N_EDGES) atomicAdd(&deg[edge_dst[idx]], 1);
    if (idx >= N_NODES * 32) return;
    int row = idx >> 5, c4 = (idx & 31) * 4;
    float4 v = *(const float4*)(x + row * 128 + c4);
    unsigned lo = (unsigned)f2b(v.x) | ((unsigned)f2b(v.y) << 16);
    unsigned hi = (unsigned)f2b(v.z) | ((unsigned)f2b(v.w) << 16);
    uint2 o; o.x = lo; o.y = hi;
    *(uint2*)(A1 + row * 256 + c4) = o;
    *(uint2*)(xb16 + row * 128 + c4) = o;
}

// ---- build transposed bf16 weights ----
__global__ void k_prep_w(const float* __restrict__ Ws1, const float* __restrict__ Wn1,
                         const float* __restrict__ Ws2, const float* __restrict__ Wn2,
                         const float* __restrict__ Wd1, const float* __restrict__ Wd2,
                         unsigned short* __restrict__ WT1, unsigned short* __restrict__ WT2,
                         unsigned short* __restrict__ WdT1, unsigned short* __restrict__ WdT2) {
    int id = blockIdx.x * blockDim.x + threadIdx.x;
    if (id < 32768) {
        int k = id & 255, n = id >> 8;
        float v = (k < 128) ? Ws1[k * 128 + n] : Wn1[(k - 128) * 128 + n];
        WT1[n * 256 + k] = f2b(v);
    } else if (id < 65536) {
        int r = id - 32768; int k = r & 255, n = r >> 8;
        float v = (k < 128) ? Ws2[k * 128 + n] : Wn2[(k - 128) * 128 + n];
        WT2[n * 256 + k] = f2b(v);
    } else if (id < 81920) {
        int r = id - 65536; int k = r & 127, n = r >> 7;
        WdT1[n * 128 + k] = f2b(Wd1[k * 128 + n]);
    } else if (id < 98304) {
        int r = id - 81920; int k = r & 127, n = r >> 7;
        WdT2[n * 128 + k] = f2b(Wd2[k * 128 + n]);
    }
}

// ---- CSR build ----
__global__ void k_scan1(const int* __restrict__ deg, int* __restrict__ row_ptr,
                        int* __restrict__ bsum, int n) {
    __shared__ int tmp[1024];
    int i = blockIdx.x * 1024 + threadIdx.x;
    int d = (i < n) ? deg[i] : 0;
    tmp[threadIdx.x] = d;
    __syncthreads();
    int run = d;
    for (int off = 1; off < 1024; off <<= 1) {
        int t = (threadIdx.x >= off) ? tmp[threadIdx.x - off] : 0;
        __syncthreads();
        run += t;
        tmp[threadIdx.x] = run;
        __syncthreads();
    }
    if (i < n) row_ptr[i] = run - d;
    if (threadIdx.x == 1023) bsum[blockIdx.x] = run;
}

__global__ void k_add(int* __restrict__ row_ptr, int* __restrict__ cursor,
                      const int* __restrict__ bsum, int n) {
    __shared__ int prefix;
    if (threadIdx.x == 0) {
        int acc = 0;
        for (int j = 0; j < (int)blockIdx.x; j++) acc += bsum[j];
        prefix = acc;
    }
    __syncthreads();
    int i = blockIdx.x * 1024 + threadIdx.x;
    if (i < n) {
        int v = row_ptr[i] + prefix;
        row_ptr[i] = v;
        cursor[i] = v;
    }
    if (i == 0) row_ptr[n] = N_EDGES;
}

__global__ void k_scatter(const int* __restrict__ src, const int* __restrict__ dst,
                          int* __restrict__ cursor, int* __restrict__ colA) {
    int e = blockIdx.x * blockDim.x + threadIdx.x;
    if (e < N_EDGES) {
        int d = dst[e];
        int slot = atomicAdd(&cursor[d], 1);
        colA[slot] = src[e];
    }
}

// ---- mean aggregation (bf16 input): 4 nodes per wave (16 lanes x 16B each).
// __launch_bounds__(256,2): allow up to 256 VGPR so all 16 gathers stay in flight.
__global__ __launch_bounds__(256, 2) void k_agg(const unsigned short* __restrict__ hb, int ldh,
                                                const int* __restrict__ row_ptr,
                                                const int* __restrict__ colA,
                                                unsigned short* __restrict__ outm, int ldo) {
    int wave = (blockIdx.x * blockDim.x + threadIdx.x) >> 6;
    int lane = threadIdx.x & 63;
    int q = lane >> 4, ql = lane & 15;
    int w = wave * 4 + q;
    if (w >= N_NODES) w = N_NODES - 1;
    int s = row_ptr[w], e = row_ptr[w + 1];
    float a[8];
#pragma unroll
    for (int j = 0; j < 8; j++) a[j] = 0.f;
    for (int base = s; base < e; base += 16) {
        int ce = (base + ql < e) ? colA[base + ql] : 0;
        int cnt = min(16, e - base);
        int ei[16];
#pragma unroll
        for (int j = 0; j < 16; j++) {
            int sl = (j < cnt) ? j : (cnt - 1);
            ei[j] = __shfl(ce, (q << 4) + sl, 64);
        }
        uint4 v[16];
#pragma unroll
        for (int j = 0; j < 16; j++)
            v[j] = *(const uint4*)(hb + (size_t)ei[j] * ldh + ql * 8);
#pragma unroll
        for (int j = 0; j < 16; j += 2) {
            const unsigned* p0 = (const unsigned*)&v[j];
            const unsigned* p1 = (const unsigned*)&v[j + 1];
            if (j + 1 < cnt) {
#pragma unroll
                for (int t = 0; t < 4; t++) {
                    a[2 * t] += b2f(p0[t] & 0xffff) + b2f(p1[t] & 0xffff);
                    a[2 * t + 1] += b2f(p0[t] >> 16) + b2f(p1[t] >> 16);
                }
            } else if (j < cnt) {
#pragma unroll
                for (int t = 0; t < 4; t++) {
                    a[2 * t] += b2f(p0[t] & 0xffff);
                    a[2 * t + 1] += b2f(p0[t] >> 16);
                }
            }
        }
    }
    float rd = 1.0f / (float)max(e - s, 1);
    uint4 o;
    unsigned* op = (unsigned*)&o;
#pragma unroll
    for (int t = 0; t < 4; t++)
        op[t] = (unsigned)f2b(a[2 * t] * rd) | ((unsigned)f2b(a[2 * t + 1] * rd) << 16);
    *(uint4*)(outm + (size_t)w * ldo + ql * 8) = o;
}

// ---- SAGE layer GEMM: 32 rows/wave, weight frags grouped 8-in-flight ----
__global__ __launch_bounds__(256) void k_gemm(const unsigned short* __restrict__ A, int lda, int K,
                                              const unsigned short* __restrict__ BT,
                                              const float* __restrict__ bias,
                                              unsigned short* __restrict__ Hout, int ldo,
                                              int M, int relu) {
    int wv = threadIdx.x >> 6, lane = threadIdx.x & 63;
    int lr = lane & 15, lq = lane >> 4;
    int r0 = blockIdx.x * 128 + wv * 32;
    int arow0 = min(r0 + lr, M - 1);
    int arow1 = min(r0 + 16 + lr, M - 1);
    f32x4 acc[2][8];
    f32x4 zero = {0.f, 0.f, 0.f, 0.f};
#pragma unroll
    for (int m = 0; m < 2; m++)
#pragma unroll
        for (int ct = 0; ct < 8; ct++) acc[m][ct] = zero;
    for (int kb = 0; kb < K; kb += 32) {
        int ka = kb + lq * 8;
        bf16x8 wf[8];
#pragma unroll
        for (int ct = 0; ct < 8; ct++)
            wf[ct] = *(const bf16x8*)(BT + (ct * 16 + lr) * K + ka);
        bf16x8 af0 = *(const bf16x8*)(A + (size_t)arow0 * lda + ka);
        bf16x8 af1 = *(const bf16x8*)(A + (size_t)arow1 * lda + ka);
#pragma unroll
        for (int ct = 0; ct < 8; ct++) {
            acc[0][ct] = __builtin_amdgcn_mfma_f32_16x16x32_bf16(af0, wf[ct], acc[0][ct], 0, 0, 0);
            acc[1][ct] = __builtin_amdgcn_mfma_f32_16x16x32_bf16(af1, wf[ct], acc[1][ct], 0, 0, 0);
        }
    }
#pragma unroll
    for (int m = 0; m < 2; m++) {
#pragma unroll
        for (int ct = 0; ct < 8; ct++) {
            int colc = ct * 16 + lr;
            float bv = bias[colc];
#pragma unroll
            for (int r = 0; r < 4; r++) {
                int row = r0 + m * 16 + lq * 4 + r;
                if (row < M) {
                    float v = acc[m][ct][r] + bv;
                    if (relu) v = fmaxf(v, 0.f);
                    Hout[(size_t)row * ldo + colc] = f2b(v);
                }
            }
        }
    }
}

// ---- decoder MLP: 1-wave blocks, fused register gather.
// __launch_bounds__(64,1): free the register allocator (cap 512) so the
// 16 gather uint4s + acc + weight frags can all be live -> all misses in flight.
__global__ __launch_bounds__(64, 1) void k_mlp(const unsigned short* __restrict__ h2b,
                                               const int* __restrict__ pos_src,
                                               const int* __restrict__ pos_dst,
                                               const int* __restrict__ neg_src,
                                               const int* __restrict__ neg_dst,
                                               const unsigned short* __restrict__ WdT1,
                                               const unsigned short* __restrict__ WdT2,
                                               const float* __restrict__ bd1,
                                               const float* __restrict__ bd2,
                                               const float* __restrict__ Wd3,
                                               const float* __restrict__ bd3,
                                               float* __restrict__ out, int P2) {
    __shared__ unsigned short t1[32][136];   // 8,704 B
    const int lane = threadIdx.x & 63, lr = lane & 15, lq = lane >> 4;
    const int row0 = blockIdx.x * 32;
    int p0 = min(row0 + lr, P2 - 1);
    int p1 = min(row0 + 16 + lr, P2 - 1);
    int s0i = (p0 < N_PAIRS) ? pos_src[p0] : neg_src[p0 - N_PAIRS];
    int d0i = (p0 < N_PAIRS) ? pos_dst[p0] : neg_dst[p0 - N_PAIRS];
    int s1i = (p1 < N_PAIRS) ? pos_src[p1] : neg_src[p1 - N_PAIRS];
    int d1i = (p1 < N_PAIRS) ? pos_dst[p1] : neg_dst[p1 - N_PAIRS];
    uint4 za0[4], zb0[4], za1[4], zb1[4];
#pragma unroll
    for (int kb = 0; kb < 4; kb++) {
        int ka = kb * 32 + lq * 8;
        za0[kb] = *(const uint4*)(h2b + (size_t)s0i * 128 + ka);
        zb0[kb] = *(const uint4*)(h2b + (size_t)d0i * 128 + ka);
        za1[kb] = *(const uint4*)(h2b + (size_t)s1i * 128 + ka);
        zb1[kb] = *(const uint4*)(h2b + (size_t)d1i * 128 + ka);
    }
    bf16x8 af0[4], af1[4];
#pragma unroll
    for (int kb = 0; kb < 4; kb++) {
        unsigned r0v[4], r1v[4];
        const unsigned* a0p = (const unsigned*)&za0[kb];
        const unsigned* b0p = (const unsigned*)&zb0[kb];
        const unsigned* a1p = (const unsigned*)&za1[kb];
        const unsigned* b1p = (const unsigned*)&zb1[kb];
#pragma unroll
        for (int j = 0; j < 4; j++) {
            unsigned short lo0 = f2b(b2f(a0p[j] & 0xffff) * b2f(b0p[j] & 0xffff));
            unsigned short hi0 = f2b(b2f(a0p[j] >> 16) * b2f(b0p[j] >> 16));
            r0v[j] = (unsigned)lo0 | ((unsigned)hi0 << 16);
            unsigned short lo1 = f2b(b2f(a1p[j] & 0xffff) * b2f(b1p[j] & 0xffff));
            unsigned short hi1 = f2b(b2f(a1p[j] >> 16) * b2f(b1p[j] >> 16));
            r1v[j] = (unsigned)lo1 | ((unsigned)hi1 << 16);
        }
        af0[kb] = *(const bf16x8*)r0v;
        af1[kb] = *(const bf16x8*)r1v;
    }
    f32x4 zero = {0.f, 0.f, 0.f, 0.f};
    f32x4 acc[2][8];
#pragma unroll
    for (int m = 0; m < 2; m++)
#pragma unroll
        for (int ct = 0; ct < 8; ct++) acc[m][ct] = zero;
#pragma unroll
    for (int kb = 0; kb < 4; kb++) {
        int ka = kb * 32 + lq * 8;
        bf16x8 wf[8];
#pragma unroll
        for (int ct = 0; ct < 8; ct++)
            wf[ct] = *(const bf16x8*)(WdT1 + (ct * 16 + lr) * 128 + ka);
#pragma unroll
        for (int ct = 0; ct < 8; ct++) {
            acc[0][ct] = __builtin_amdgcn_mfma_f32_16x16x32_bf16(af0[kb], wf[ct], acc[0][ct], 0, 0, 0);
            acc[1][ct] = __builtin_amdgcn_mfma_f32_16x16x32_bf16(af1[kb], wf[ct], acc[1][ct], 0, 0, 0);
        }
    }
#pragma unroll
    for (int m = 0; m < 2; m++)
#pragma unroll
        for (int ct = 0; ct < 8; ct++) {
            int colc = ct * 16 + lr;
            float bv = bd1[colc];
#pragma unroll
            for (int r = 0; r < 4; r++) {
                float v = fmaxf(acc[m][ct][r] + bv, 0.f);
                t1[m * 16 + lq * 4 + r][colc] = f2b(v);
            }
        }
    __syncthreads();
#pragma unroll
    for (int m = 0; m < 2; m++)
#pragma unroll
        for (int ct = 0; ct < 8; ct++) acc[m][ct] = zero;
#pragma unroll
    for (int kb = 0; kb < 4; kb++) {
        int ka = kb * 32 + lq * 8;
        bf16x8 wf[8];
#pragma unroll
        for (int ct = 0; ct < 8; ct++)
            wf[ct] = *(const bf16x8*)(WdT2 + (ct * 16 + lr) * 128 + ka);
        bf16x8 bf0 = *(const bf16x8*)(&t1[lr][ka]);
        bf16x8 bf1 = *(const bf16x8*)(&t1[16 + lr][ka]);
#pragma unroll
        for (int ct = 0; ct < 8; ct++) {
            acc[0][ct] = __builtin_amdgcn_mfma_f32_16x16x32_bf16(bf0, wf[ct], acc[0][ct], 0, 0, 0);
            acc[1][ct] = __builtin_amdgcn_mfma_f32_16x16x32_bf16(bf1, wf[ct], acc[1][ct], 0, 0, 0);
        }
    }
    float sc[2][4] = {{0.f, 0.f, 0.f, 0.f}, {0.f, 0.f, 0.f, 0.f}};
#pragma unroll
    for (int ct = 0; ct < 8; ct++) {
        int colc = ct * 16 + lr;
        float bv = bd2[colc];
        float w3 = Wd3[colc];
#pragma unroll
        for (int m = 0; m < 2; m++)
#pragma unroll
            for (int r = 0; r < 4; r++) {
                float v = fmaxf(acc[m][ct][r] + bv, 0.f);
                sc[m][r] += v * w3;
            }
    }
#pragma unroll
    for (int mm = 1; mm < 16; mm <<= 1)
#pragma unroll
        for (int m = 0; m < 2; m++)
#pragma unroll
            for (int r = 0; r < 4; r++) sc[m][r] += __shfl_xor(sc[m][r], mm, 64);
    if (lr == 0) {
        float b3 = bd3[0];
#pragma unroll
        for (int m = 0; m < 2; m++)
#pragma unroll
            for (int r = 0; r < 4; r++) {
                int g = row0 + m * 16 + lq * 4 + r;
                if (g < P2) out[g] = sc[m][r] + b3;
            }
    }
}

static inline size_t alignup(size_t v) { return (v + 255) & ~(size_t)255; }

extern "C" void kernel_launch(void* const* d_in, const int* in_sizes, int n_in,
                              void* d_out, int out_size, void* d_ws, size_t ws_size,
                              hipStream_t stream) {
    const float* x = (const float*)d_in[0];
    const int* edge_src = (const int*)d_in[1];
    const int* edge_dst = (const int*)d_in[2];
    const int* pos_src = (const int*)d_in[3];
    const int* pos_dst = (const int*)d_in[4];
    const int* neg_src = (const int*)d_in[5];
    const int* neg_dst = (const int*)d_in[6];
    const float* Ws1 = (const float*)d_in[7];
    const float* Wn1 = (const float*)d_in[8];
    const float* b1 = (const float*)d_in[9];
    const float* Ws2 = (const float*)d_in[10];
    const float* Wn2 = (const float*)d_in[11];
    const float* b2 = (const float*)d_in[12];
    const float* Wd1 = (const float*)d_in[13];
    const float* bd1 = (const float*)d_in[14];
    const float* Wd2 = (const float*)d_in[15];
    const float* bd2 = (const float*)d_in[16];
    const float* Wd3 = (const float*)d_in[17];
    const float* bd3 = (const float*)d_in[18];
    float* out = (float*)d_out;

    char* p = (char*)d_ws;
    int* deg = (int*)p;            p += alignup(N_NODES * 4);
    int* row_ptr = (int*)p;        p += alignup((N_NODES + 1) * 4);
    int* cursor = (int*)p;         p += alignup(N_NODES * 4);
    int* bsum = (int*)p;           p += alignup(64 * 4);
    int* colA = (int*)p;           p += alignup(N_EDGES * 4);
    unsigned short* A1 = (unsigned short*)p;  p += alignup((size_t)N_NODES * 256 * 2);
    unsigned short* A2 = (unsigned short*)p;  p += alignup((size_t)N_NODES * 256 * 2);
    unsigned short* h2b = (unsigned short*)p; p += alignup((size_t)N_NODES * 128 * 2);
    unsigned short* WT1 = (unsigned short*)p;  p += alignup(32768 * 2);
    unsigned short* WT2 = (unsigned short*)p;  p += alignup(32768 * 2);
    unsigned short* WdT1 = (unsigned short*)p; p += alignup(16384 * 2);
    unsigned short* WdT2 = (unsigned short*)p; p += alignup(16384 * 2);
    unsigned short* xb16 = h2b;   // aliased: consumed by agg1 before gemm2 writes h2b

    hipMemsetAsync(deg, 0, N_NODES * 4, stream);

    k_convert_x<<<(N_NODES * 32 + 255) / 256, 256, 0, stream>>>(x, A1, xb16, edge_dst, deg);
    k_prep_w<<<384, 256, 0, stream>>>(Ws1, Wn1, Ws2, Wn2, Wd1, Wd2, WT1, WT2, WdT1, WdT2);

    int nb1 = (N_NODES + 1023) / 1024;
    k_scan1<<<nb1, 1024, 0, stream>>>(deg, row_ptr, bsum, N_NODES);
    k_add<<<nb1, 1024, 0, stream>>>(row_ptr, cursor, bsum, N_NODES);
    k_scatter<<<(N_EDGES + 255) / 256, 256, 0, stream>>>(edge_src, edge_dst, cursor, colA);

    int nagg = (N_NODES + 15) / 16;

    // layer 1 (bf16 aggregation from compact xb16)
    k_agg<<<nagg, 256, 0, stream>>>(xb16, 128, row_ptr, colA, A1 + 128, 256);
    k_gemm<<<(N_NODES + 127) / 128, 256, 0, stream>>>(A1, 256, 256, WT1, b1, A2, 256, N_NODES, 1);

    // layer 2
    k_agg<<<nagg, 256, 0, stream>>>(A2, 256, row_ptr, colA, A2 + 128, 256);
    k_gemm<<<(N_NODES + 127) / 128, 256, 0, stream>>>(A2, 256, 256, WT2, b2, h2b, 128, N_NODES, 0);

    // decoder: fused gather + MLP, 32 pairs per 1-wave block
    k_mlp<<<(N_PAIRS * 2 + 31) / 32, 64, 0, stream>>>(h2b, pos_src, pos_dst, neg_src, neg_dst,
                                                      WdT1, WdT2, bd1, bd2, Wd3, bd3,
                                                      out, N_PAIRS * 2);
}